// Round 9
// baseline (406.120 us; speedup 1.0000x reference)
//
#include <hip/hip_runtime.h>

#define NN 8192
#define NF4 2048              // f32x4 (and u32) per row
#define NQ4 512               // u32x4 (16 fp8) per row
#define THREADS 256
#define RED_Y 32
constexpr float EPS = 1e-4f;
constexpr float QSCALE = 16.0f;  // power of 2: cancels exactly in r*c

typedef float        f32x4 __attribute__((ext_vector_type(4)));
typedef unsigned int u32x4 __attribute__((ext_vector_type(4)));

// ---------------------------------------------------------------------------
// out_ij = (A_ij+EPS)*r_i*c_j. Pair pass p: r_i = 1/((A+e)_i . c); partial
// col sums += r_i*(A+e)_ij. Pass 0 reads fp32 A once, emits Q = fp8_e4m3
// (QSCALE*(A+EPS)); passes 1-4 read Q (64 MB, L3-resident); finalize reads
// fp32 A (exact epilogue). Partial layout slot-permuted (slot = w*512+u for
// true f32x4 idx u*4+w) so pair stores are coalesced; k_red un-permutes.
//
// HARD-WON (R6/R7): launch_bounds' 2nd arg is a VGPR CAP (512/N), not an
// occupancy dial. Bound 4 on fat pair kernels -> accumulator spills in the
// hot loop (874/623us vs 262us). Keep bound 2 on pair kernels.
// HARD-WON (R8): pair_q 1024 blocks/RPB 8 is WORSE (346us): per-block fixed
// cost (full-c creg load + partial slice) doubles. 512 blocks/RPB 16 is opt.
// This round: R5 pair kernels exactly + fused k_red (launch-count 16 -> 11).
// ---------------------------------------------------------------------------

__device__ __forceinline__ unsigned int pack4(f32x4 v) {
    int r = 0;
    r = __builtin_amdgcn_cvt_pk_fp8_f32(v.x, v.y, r, false);  // bytes 0-1
    r = __builtin_amdgcn_cvt_pk_fp8_f32(v.z, v.w, r, true);   // bytes 2-3
    return (unsigned int)r;
}

__device__ __forceinline__ f32x4 unpack4(unsigned int u) {
    auto lo = __builtin_amdgcn_cvt_pk_f32_fp8(u, false);  // native float2 vec
    auto hi = __builtin_amdgcn_cvt_pk_f32_fp8(u, true);
    f32x4 r;
    r.x = lo[0]; r.y = lo[1]; r.z = hi[0]; r.w = hi[1];
    return r;
}

// fp32-A pair pass, 512 blocks, 16 rows/block. FIRST: c==ones (zero counters).
template <bool FIRST, bool REV, bool WQ>
__global__ __launch_bounds__(THREADS, 2)
void k_pair_a(const float* __restrict__ A, unsigned int* __restrict__ Q,
              const float* __restrict__ c, float* __restrict__ r_out,
              float* __restrict__ partial, unsigned int* __restrict__ counters) {
    const int t = threadIdx.x;
    if (FIRST && blockIdx.x == 0 && t < 8) counters[t] = 0;  // k_red runs later
    const f32x4* A4 = reinterpret_cast<const f32x4*>(A);
    f32x4 creg[8];
    if constexpr (!FIRST) {
        const f32x4* c4 = reinterpret_cast<const f32x4*>(c);
        #pragma unroll
        for (int g = 0; g < 8; ++g) creg[g] = c4[g * THREADS + t];
    }
    float acc[8][4];
    #pragma unroll
    for (int g = 0; g < 8; ++g)
        #pragma unroll
        for (int k = 0; k < 4; ++k) acc[g][k] = 0.f;

    __shared__ float smem[2][4][2];
    __shared__ float lbuf[NN];   // 32 KB: slot-reorder staging for partial
    const int lane = t & 63, wid = t >> 6;
    const int base = REV ? NN - (blockIdx.x + 1) * 16 : blockIdx.x * 16;

    for (int rr = 0; rr < 16; rr += 2) {   // runtime loop: no reg explosion
        const size_t i0 = (size_t)(base + rr) * NF4;
        const size_t i1 = i0 + NF4;
        f32x4 e0[8], e1[8];
        #pragma unroll
        for (int g = 0; g < 8; ++g) {
            e0[g] = __builtin_nontemporal_load(A4 + i0 + g * THREADS + t) + EPS;
            e1[g] = __builtin_nontemporal_load(A4 + i1 + g * THREADS + t) + EPS;
        }
        float p0 = 0.f, p1 = 0.f;
        #pragma unroll
        for (int g = 0; g < 8; ++g) {
            if constexpr (FIRST) {
                p0 += e0[g].x + e0[g].y + e0[g].z + e0[g].w;
                p1 += e1[g].x + e1[g].y + e1[g].z + e1[g].w;
            } else {
                p0 += e0[g].x * creg[g].x + e0[g].y * creg[g].y
                    + e0[g].z * creg[g].z + e0[g].w * creg[g].w;
                p1 += e1[g].x * creg[g].x + e1[g].y * creg[g].y
                    + e1[g].z * creg[g].z + e1[g].w * creg[g].w;
            }
        }
        #pragma unroll
        for (int off = 32; off > 0; off >>= 1) {
            p0 += __shfl_down(p0, off);
            p1 += __shfl_down(p1, off);
        }
        const int buf = (rr >> 1) & 1;
        if (lane == 0) { smem[buf][wid][0] = p0; smem[buf][wid][1] = p1; }
        __syncthreads();
        const float ri0 = 1.f / (smem[buf][0][0] + smem[buf][1][0] +
                                 smem[buf][2][0] + smem[buf][3][0]);
        const float ri1 = 1.f / (smem[buf][0][1] + smem[buf][1][1] +
                                 smem[buf][2][1] + smem[buf][3][1]);
        if (t == 0) { r_out[base + rr] = ri0; r_out[base + rr + 1] = ri1; }
        if constexpr (WQ) {
            #pragma unroll
            for (int g = 0; g < 8; ++g) {
                Q[i0 + g * THREADS + t] = pack4(e0[g] * QSCALE);
                Q[i1 + g * THREADS + t] = pack4(e1[g] * QSCALE);
            }
        }
        #pragma unroll
        for (int g = 0; g < 8; ++g) {
            acc[g][0] += ri0 * e0[g].x + ri1 * e1[g].x;
            acc[g][1] += ri0 * e0[g].y + ri1 * e1[g].y;
            acc[g][2] += ri0 * e0[g].z + ri1 * e1[g].z;
            acc[g][3] += ri0 * e0[g].w + ri1 * e1[g].w;
        }
    }
    // restage through LDS so global partial stores are slot-ordered/coalesced
    f32x4* L4 = reinterpret_cast<f32x4*>(lbuf);
    #pragma unroll
    for (int g = 0; g < 8; ++g) {
        f32x4 v;
        v.x = acc[g][0]; v.y = acc[g][1]; v.z = acc[g][2]; v.w = acc[g][3];
        L4[g * THREADS + t] = v;
    }
    __syncthreads();
    f32x4* P4 = reinterpret_cast<f32x4*>(partial);
    #pragma unroll
    for (int g = 0; g < 2; ++g)
        #pragma unroll
        for (int w = 0; w < 4; ++w) {
            f32x4 v = L4[(g * THREADS + t) * 4 + w];
            P4[(size_t)blockIdx.x * NF4 + w * NQ4 + g * THREADS + t] = v;
        }
}

// fp8-Q pair pass (passes 1-4). 512 blocks, 16 rows/block, bound 2. R5-exact.
template <bool REV>
__global__ __launch_bounds__(THREADS, 2)
void k_pair_q(const unsigned int* __restrict__ Q, const float* __restrict__ c,
              float* __restrict__ r_out, float* __restrict__ partial) {
    const int t = threadIdx.x;
    const u32x4* Q4 = reinterpret_cast<const u32x4*>(Q);
    const f32x4* c4 = reinterpret_cast<const f32x4*>(c);
    f32x4 creg[2][4];
    #pragma unroll
    for (int g = 0; g < 2; ++g)
        #pragma unroll
        for (int j = 0; j < 4; ++j)
            creg[g][j] = c4[(size_t)(g * THREADS + t) * 4 + j];
    float acc[2][16];
    #pragma unroll
    for (int g = 0; g < 2; ++g)
        #pragma unroll
        for (int k = 0; k < 16; ++k) acc[g][k] = 0.f;

    __shared__ float smem[2][4][2];
    const int lane = t & 63, wid = t >> 6;
    const int base = REV ? NN - (blockIdx.x + 1) * 16 : blockIdx.x * 16;

    for (int rr = 0; rr < 16; rr += 2) {   // runtime loop: no reg explosion
        const size_t i0 = (size_t)(base + rr) * NQ4;
        const size_t i1 = i0 + NQ4;
        u32x4 q0[2], q1[2];
        #pragma unroll
        for (int g = 0; g < 2; ++g) {
            q0[g] = Q4[i0 + g * THREADS + t];
            q1[g] = Q4[i1 + g * THREADS + t];
        }
        float p0 = 0.f, p1 = 0.f;
        #pragma unroll
        for (int g = 0; g < 2; ++g)
            #pragma unroll
            for (int w = 0; w < 4; ++w) {
                f32x4 v0 = unpack4(q0[g][w]);
                f32x4 v1 = unpack4(q1[g][w]);
                p0 += v0.x * creg[g][w].x + v0.y * creg[g][w].y
                    + v0.z * creg[g][w].z + v0.w * creg[g][w].w;
                p1 += v1.x * creg[g][w].x + v1.y * creg[g][w].y
                    + v1.z * creg[g][w].z + v1.w * creg[g][w].w;
            }
        #pragma unroll
        for (int off = 32; off > 0; off >>= 1) {
            p0 += __shfl_down(p0, off);
            p1 += __shfl_down(p1, off);
        }
        const int buf = (rr >> 1) & 1;
        if (lane == 0) { smem[buf][wid][0] = p0; smem[buf][wid][1] = p1; }
        __syncthreads();
        const float ri0 = 1.f / (smem[buf][0][0] + smem[buf][1][0] +
                                 smem[buf][2][0] + smem[buf][3][0]);
        const float ri1 = 1.f / (smem[buf][0][1] + smem[buf][1][1] +
                                 smem[buf][2][1] + smem[buf][3][1]);
        if (t == 0) {
            r_out[base + rr]     = ri0 * QSCALE;   // true-scale r
            r_out[base + rr + 1] = ri1 * QSCALE;
        }
        #pragma unroll
        for (int g = 0; g < 2; ++g)
            #pragma unroll
            for (int w = 0; w < 4; ++w) {
                f32x4 v0 = unpack4(q0[g][w]);
                f32x4 v1 = unpack4(q1[g][w]);
                acc[g][w * 4 + 0] += ri0 * v0.x + ri1 * v1.x;
                acc[g][w * 4 + 1] += ri0 * v0.y + ri1 * v1.y;
                acc[g][w * 4 + 2] += ri0 * v0.z + ri1 * v1.z;
                acc[g][w * 4 + 3] += ri0 * v0.w + ri1 * v1.w;
            }
    }
    f32x4* P4 = reinterpret_cast<f32x4*>(partial);
    #pragma unroll
    for (int g = 0; g < 2; ++g)
        #pragma unroll
        for (int w = 0; w < 4; ++w) {
            f32x4 v;
            v.x = acc[g][w * 4 + 0]; v.y = acc[g][w * 4 + 1];
            v.z = acc[g][w * 4 + 2]; v.w = acc[g][w * 4 + 3];
            P4[(size_t)blockIdx.x * NF4 + w * NQ4 + g * THREADS + t] = v;
        }
}

// Fused two-stage reduce, grid (8, RED_Y). Stage A: block (x,y) sums its 16
// slices for slot chunk x -> partial2[y]. Stage B: last block per chunk
// (atomic election, agent scope) sums RED_Y rows, reciprocal, un-permute.
// Sum order identical to the old red1+red2 -> c is bit-identical.
__global__ __launch_bounds__(THREADS, 4)
void k_red(const float* __restrict__ partial, float* __restrict__ partial2,
           float* __restrict__ c, unsigned int* __restrict__ counters) {
    const int x = blockIdx.x, y = blockIdx.y;
    const int slot = x * THREADS + threadIdx.x;   // f32x4 slot 0..2047
    const int slices = 512 / RED_Y;               // 16
    const f32x4* P = reinterpret_cast<const f32x4*>(partial);
    f32x4 acc = {0.f, 0.f, 0.f, 0.f};
    #pragma unroll 4
    for (int s = y * slices; s < (y + 1) * slices; ++s)
        acc += P[(size_t)s * NF4 + slot];
    reinterpret_cast<f32x4*>(partial2)[(size_t)y * NF4 + slot] = acc;

    __shared__ int is_last;
    __threadfence();   // release stage-A write (device scope)
    if (threadIdx.x == 0) {
        unsigned int prev = __hip_atomic_fetch_add(&counters[x], 1u,
                                __ATOMIC_ACQ_REL, __HIP_MEMORY_SCOPE_AGENT);
        is_last = (prev == RED_Y - 1);
    }
    __syncthreads();
    if (!is_last) return;
    if (threadIdx.x == 0)   // self-reset for the next pass
        __hip_atomic_store(&counters[x], 0u, __ATOMIC_RELAXED,
                           __HIP_MEMORY_SCOPE_AGENT);
    __threadfence();   // acquire side
    const f32x4* P2 = reinterpret_cast<const f32x4*>(partial2);
    f32x4 a2 = {0.f, 0.f, 0.f, 0.f};
    #pragma unroll
    for (int s = 0; s < RED_Y; ++s) a2 += P2[(size_t)s * NF4 + slot];
    f32x4 o;
    o.x = 1.f / a2.x; o.y = 1.f / a2.y; o.z = 1.f / a2.z; o.w = 1.f / a2.w;
    const int w = slot >> 9, u = slot & 511;      // un-permute slot
    reinterpret_cast<f32x4*>(c)[u * 4 + w] = o;
}

// exact fp32 epilogue from A
__global__ __launch_bounds__(THREADS, 4)
void k_finalize(const float* __restrict__ A, const float* __restrict__ r,
                const float* __restrict__ c, float* __restrict__ out) {
    const f32x4* A4 = reinterpret_cast<const f32x4*>(A);
    const f32x4* c4 = reinterpret_cast<const f32x4*>(c);
    f32x4* O4 = reinterpret_cast<f32x4*>(out);
    const size_t total = (size_t)NN * NF4;
    const size_t stride = (size_t)gridDim.x * THREADS;
    for (size_t k = (size_t)blockIdx.x * THREADS + threadIdx.x; k < total;
         k += stride) {
        const int row = (int)(k >> 11);
        const int jc = (int)(k & 2047);
        f32x4 a = __builtin_nontemporal_load(A4 + k);
        f32x4 w = c4[jc];
        const float s = r[row];
        f32x4 o = (a + EPS) * (s * w);
        __builtin_nontemporal_store(o, O4 + k);
    }
}

extern "C" void kernel_launch(void* const* d_in, const int* in_sizes, int n_in,
                              void* d_out, int out_size, void* d_ws, size_t ws_size,
                              hipStream_t stream) {
    (void)in_sizes; (void)n_in; (void)out_size;
    const float* A = (const float*)d_in[0];
    float* out = (float*)d_out;
    const dim3 gred(NF4 / THREADS, RED_Y);   // (8, 32)

    const size_t q_bytes = (size_t)NN * NN;  // 64 MB
    const size_t fixed_b = (size_t)(2 * NN + RED_Y * NN) * sizeof(float) + 256;
    const size_t part_b  = (size_t)512 * NN * sizeof(float);

    if (ws_size >= q_bytes + fixed_b + part_b) {
        char* p = (char*)d_ws;
        unsigned int* Q = (unsigned int*)p;  p += q_bytes;
        float* r = (float*)p;                p += NN * sizeof(float);
        float* c = (float*)p;                p += NN * sizeof(float);
        float* partial2 = (float*)p;         p += (size_t)RED_Y * NN * sizeof(float);
        unsigned int* counters = (unsigned int*)p;  p += 256;
        float* partial = (float*)p;

        k_pair_a<true, false, true><<<512, THREADS, 0, stream>>>(
            A, Q, nullptr, r, partial, counters);
        k_red<<<gred, THREADS, 0, stream>>>(partial, partial2, c, counters);
        for (int ppass = 1; ppass < 5; ++ppass) {
            if (ppass & 1)
                k_pair_q<true><<<512, THREADS, 0, stream>>>(Q, c, r, partial);
            else
                k_pair_q<false><<<512, THREADS, 0, stream>>>(Q, c, r, partial);
            k_red<<<gred, THREADS, 0, stream>>>(partial, partial2, c, counters);
        }
        k_finalize<<<2048, THREADS, 0, stream>>>(A, r, c, out);
    } else {
        // fp32 fallback: all passes read A directly
        char* p = (char*)d_ws;
        float* r = (float*)p;                p += NN * sizeof(float);
        float* c = (float*)p;                p += NN * sizeof(float);
        float* partial2 = (float*)p;         p += (size_t)RED_Y * NN * sizeof(float);
        unsigned int* counters = (unsigned int*)p;  p += 256;
        float* partial = (float*)p;

        k_pair_a<true, false, false><<<512, THREADS, 0, stream>>>(
            A, nullptr, nullptr, r, partial, counters);
        k_red<<<gred, THREADS, 0, stream>>>(partial, partial2, c, counters);
        for (int ppass = 1; ppass < 5; ++ppass) {
            if (ppass & 1)
                k_pair_a<false, true, false><<<512, THREADS, 0, stream>>>(
                    A, nullptr, c, r, partial, counters);
            else
                k_pair_a<false, false, false><<<512, THREADS, 0, stream>>>(
                    A, nullptr, c, r, partial, counters);
            k_red<<<gred, THREADS, 0, stream>>>(partial, partial2, c, counters);
        }
        k_finalize<<<2048, THREADS, 0, stream>>>(A, r, c, out);
    }
}

// Round 10
// 261.907 us; speedup vs baseline: 1.5506x; 1.5506x over previous
//
#include <hip/hip_runtime.h>

#define NN 8192
#define NF4 2048              // f32x4 (and u32) per row
#define NQ4 512               // u32x4 (16 fp8) per row
#define THREADS 256
#define NBLK 512
#define RPB 16                // rows per pair block
#define RED1_OUT 32
#define SLICES_PER (NBLK / RED1_OUT)   // 16

constexpr float EPS = 1e-4f;
constexpr float QSCALE = 16.0f;  // power of 2: cancels exactly in r*c

typedef float        f32x4 __attribute__((ext_vector_type(4)));
typedef unsigned int u32x4 __attribute__((ext_vector_type(4)));

// ---------------------------------------------------------------------------
// out_ij = (A_ij+EPS)*r_i*c_j. Pair pass p: r_i = 1/((A+e)_i . c); partial
// col sums += r_i*(A+e)_ij. Pass 0 reads fp32 A once and emits Q = fp8_e4m3
// (QSCALE*(A+EPS)); passes 1-4 read Q (64 MB, L3-resident); finalize reads
// fp32 A again (exact epilogue, no quantization error). Partial layout is
// slot-permuted (slot = w*512+u for true f32x4 idx u*4+w) so pair-kernel
// partial stores are coalesced; red2 un-permutes into c.
//
// == A/B ledger (do not re-try these) ==
// R5 = this code: 262 us  <- optimum
// R6: +full unrolls +launch_bounds(,3/4): 874 us. 2nd arg is a VGPR CAP
//     (512/N); capping a fat kernel at 128 VGPR spills accumulators into
//     the hot streaming loop. Occupancy is raised via GRID, never the cap.
// R7: bound(,4) on pair_q only: 623 us. Same spill mechanism.
// R8: pair_q 1024 blocks/RPB 8 (bound 2): 346 us. Per-block fixed cost
//     (full-c creg load + 32KB partial slice) doubles; 512/16 is optimal.
// R9: fused red1+red2 via agent-scope atomic election: 406 us. Device-scope
//     fences on MI355X = L2 writeback/invalidate (XCD L2s non-coherent) ->
//     evicts the L3/L2-resident Q. Separate launches are CHEAPER than any
//     in-kernel grid sync here.
// ---------------------------------------------------------------------------

__device__ __forceinline__ unsigned int pack4(f32x4 v) {
    int r = 0;
    r = __builtin_amdgcn_cvt_pk_fp8_f32(v.x, v.y, r, false);  // bytes 0-1
    r = __builtin_amdgcn_cvt_pk_fp8_f32(v.z, v.w, r, true);   // bytes 2-3
    return (unsigned int)r;
}

__device__ __forceinline__ f32x4 unpack4(unsigned int u) {
    auto lo = __builtin_amdgcn_cvt_pk_f32_fp8(u, false);  // native float2 vec
    auto hi = __builtin_amdgcn_cvt_pk_f32_fp8(u, true);
    f32x4 r;
    r.x = lo[0]; r.y = lo[1]; r.z = hi[0]; r.w = hi[1];
    return r;
}

// fp32-A pair pass. FIRST: c==ones. WQ: emit fp8 working copy Q.
template <bool FIRST, bool REV, bool WQ>
__global__ __launch_bounds__(THREADS, 2)
void k_pair_a(const float* __restrict__ A, unsigned int* __restrict__ Q,
              const float* __restrict__ c, float* __restrict__ r_out,
              float* __restrict__ partial) {
    const int t = threadIdx.x;
    const f32x4* A4 = reinterpret_cast<const f32x4*>(A);
    f32x4 creg[8];
    if constexpr (!FIRST) {
        const f32x4* c4 = reinterpret_cast<const f32x4*>(c);
        #pragma unroll
        for (int g = 0; g < 8; ++g) creg[g] = c4[g * THREADS + t];
    }
    float acc[8][4];
    #pragma unroll
    for (int g = 0; g < 8; ++g)
        #pragma unroll
        for (int k = 0; k < 4; ++k) acc[g][k] = 0.f;

    __shared__ float smem[2][4][2];
    __shared__ float lbuf[NN];   // 32 KB: slot-reorder staging for partial
    const int lane = t & 63, wid = t >> 6;
    const int base = REV ? NN - (blockIdx.x + 1) * RPB : blockIdx.x * RPB;

    for (int rr = 0; rr < RPB; rr += 2) {   // runtime loop: no reg explosion
        const size_t i0 = (size_t)(base + rr) * NF4;
        const size_t i1 = i0 + NF4;
        f32x4 e0[8], e1[8];
        #pragma unroll
        for (int g = 0; g < 8; ++g) {
            e0[g] = __builtin_nontemporal_load(A4 + i0 + g * THREADS + t) + EPS;
            e1[g] = __builtin_nontemporal_load(A4 + i1 + g * THREADS + t) + EPS;
        }
        float p0 = 0.f, p1 = 0.f;
        #pragma unroll
        for (int g = 0; g < 8; ++g) {
            if constexpr (FIRST) {
                p0 += e0[g].x + e0[g].y + e0[g].z + e0[g].w;
                p1 += e1[g].x + e1[g].y + e1[g].z + e1[g].w;
            } else {
                p0 += e0[g].x * creg[g].x + e0[g].y * creg[g].y
                    + e0[g].z * creg[g].z + e0[g].w * creg[g].w;
                p1 += e1[g].x * creg[g].x + e1[g].y * creg[g].y
                    + e1[g].z * creg[g].z + e1[g].w * creg[g].w;
            }
        }
        #pragma unroll
        for (int off = 32; off > 0; off >>= 1) {
            p0 += __shfl_down(p0, off);
            p1 += __shfl_down(p1, off);
        }
        const int buf = (rr >> 1) & 1;
        if (lane == 0) { smem[buf][wid][0] = p0; smem[buf][wid][1] = p1; }
        __syncthreads();
        const float ri0 = 1.f / (smem[buf][0][0] + smem[buf][1][0] +
                                 smem[buf][2][0] + smem[buf][3][0]);
        const float ri1 = 1.f / (smem[buf][0][1] + smem[buf][1][1] +
                                 smem[buf][2][1] + smem[buf][3][1]);
        if (t == 0) { r_out[base + rr] = ri0; r_out[base + rr + 1] = ri1; }
        if constexpr (WQ) {
            #pragma unroll
            for (int g = 0; g < 8; ++g) {
                Q[i0 + g * THREADS + t] = pack4(e0[g] * QSCALE);
                Q[i1 + g * THREADS + t] = pack4(e1[g] * QSCALE);
            }
        }
        #pragma unroll
        for (int g = 0; g < 8; ++g) {
            acc[g][0] += ri0 * e0[g].x + ri1 * e1[g].x;
            acc[g][1] += ri0 * e0[g].y + ri1 * e1[g].y;
            acc[g][2] += ri0 * e0[g].z + ri1 * e1[g].z;
            acc[g][3] += ri0 * e0[g].w + ri1 * e1[g].w;
        }
    }
    // restage through LDS so global partial stores are slot-ordered/coalesced
    f32x4* L4 = reinterpret_cast<f32x4*>(lbuf);
    #pragma unroll
    for (int g = 0; g < 8; ++g) {
        f32x4 v;
        v.x = acc[g][0]; v.y = acc[g][1]; v.z = acc[g][2]; v.w = acc[g][3];
        L4[g * THREADS + t] = v;
    }
    __syncthreads();
    f32x4* P4 = reinterpret_cast<f32x4*>(partial);
    #pragma unroll
    for (int g = 0; g < 2; ++g)
        #pragma unroll
        for (int w = 0; w < 4; ++w) {
            f32x4 v = L4[(g * THREADS + t) * 4 + w];
            P4[(size_t)blockIdx.x * NF4 + w * NQ4 + g * THREADS + t] = v;
        }
}

// fp8-Q pair pass (passes 1-4). ri is 1/QSCALE-scaled inside; cancels in acc.
template <bool REV>
__global__ __launch_bounds__(THREADS, 2)
void k_pair_q(const unsigned int* __restrict__ Q, const float* __restrict__ c,
              float* __restrict__ r_out, float* __restrict__ partial) {
    const int t = threadIdx.x;
    const u32x4* Q4 = reinterpret_cast<const u32x4*>(Q);
    const f32x4* c4 = reinterpret_cast<const f32x4*>(c);
    f32x4 creg[2][4];
    #pragma unroll
    for (int g = 0; g < 2; ++g)
        #pragma unroll
        for (int j = 0; j < 4; ++j)
            creg[g][j] = c4[(size_t)(g * THREADS + t) * 4 + j];
    float acc[2][16];
    #pragma unroll
    for (int g = 0; g < 2; ++g)
        #pragma unroll
        for (int k = 0; k < 16; ++k) acc[g][k] = 0.f;

    __shared__ float smem[2][4][2];
    const int lane = t & 63, wid = t >> 6;
    const int base = REV ? NN - (blockIdx.x + 1) * RPB : blockIdx.x * RPB;

    for (int rr = 0; rr < RPB; rr += 2) {   // runtime loop: no reg explosion
        const size_t i0 = (size_t)(base + rr) * NQ4;
        const size_t i1 = i0 + NQ4;
        u32x4 q0[2], q1[2];
        #pragma unroll
        for (int g = 0; g < 2; ++g) {
            q0[g] = Q4[i0 + g * THREADS + t];
            q1[g] = Q4[i1 + g * THREADS + t];
        }
        float p0 = 0.f, p1 = 0.f;
        #pragma unroll
        for (int g = 0; g < 2; ++g)
            #pragma unroll
            for (int w = 0; w < 4; ++w) {
                f32x4 v0 = unpack4(q0[g][w]);
                f32x4 v1 = unpack4(q1[g][w]);
                p0 += v0.x * creg[g][w].x + v0.y * creg[g][w].y
                    + v0.z * creg[g][w].z + v0.w * creg[g][w].w;
                p1 += v1.x * creg[g][w].x + v1.y * creg[g][w].y
                    + v1.z * creg[g][w].z + v1.w * creg[g][w].w;
            }
        #pragma unroll
        for (int off = 32; off > 0; off >>= 1) {
            p0 += __shfl_down(p0, off);
            p1 += __shfl_down(p1, off);
        }
        const int buf = (rr >> 1) & 1;
        if (lane == 0) { smem[buf][wid][0] = p0; smem[buf][wid][1] = p1; }
        __syncthreads();
        const float ri0 = 1.f / (smem[buf][0][0] + smem[buf][1][0] +
                                 smem[buf][2][0] + smem[buf][3][0]);
        const float ri1 = 1.f / (smem[buf][0][1] + smem[buf][1][1] +
                                 smem[buf][2][1] + smem[buf][3][1]);
        if (t == 0) {
            r_out[base + rr]     = ri0 * QSCALE;   // true-scale r
            r_out[base + rr + 1] = ri1 * QSCALE;
        }
        #pragma unroll
        for (int g = 0; g < 2; ++g)
            #pragma unroll
            for (int w = 0; w < 4; ++w) {
                f32x4 v0 = unpack4(q0[g][w]);
                f32x4 v1 = unpack4(q1[g][w]);
                acc[g][w * 4 + 0] += ri0 * v0.x + ri1 * v1.x;
                acc[g][w * 4 + 1] += ri0 * v0.y + ri1 * v1.y;
                acc[g][w * 4 + 2] += ri0 * v0.z + ri1 * v1.z;
                acc[g][w * 4 + 3] += ri0 * v0.w + ri1 * v1.w;
            }
    }
    f32x4* P4 = reinterpret_cast<f32x4*>(partial);
    #pragma unroll
    for (int g = 0; g < 2; ++g)
        #pragma unroll
        for (int w = 0; w < 4; ++w) {
            f32x4 v;
            v.x = acc[g][w * 4 + 0]; v.y = acc[g][w * 4 + 1];
            v.z = acc[g][w * 4 + 2]; v.w = acc[g][w * 4 + 3];
            P4[(size_t)blockIdx.x * NF4 + w * NQ4 + g * THREADS + t] = v;
        }
}

__global__ __launch_bounds__(THREADS, 4)
void k_red1(const float* __restrict__ partial, float* __restrict__ partial2) {
    const int j4 = blockIdx.x * THREADS + threadIdx.x;   // storage slot
    const int s0 = blockIdx.y * SLICES_PER;
    const f32x4* P = reinterpret_cast<const f32x4*>(partial);
    f32x4 acc = {0.f, 0.f, 0.f, 0.f};
    #pragma unroll 4
    for (int s = 0; s < SLICES_PER; ++s) acc += P[(size_t)(s0 + s) * NF4 + j4];
    reinterpret_cast<f32x4*>(partial2)[(size_t)blockIdx.y * NF4 + j4] = acc;
}

__global__ __launch_bounds__(THREADS, 4)
void k_red2(const float* __restrict__ partial2, float* __restrict__ c) {
    const int j4 = blockIdx.x * THREADS + threadIdx.x;   // storage slot
    const f32x4* P = reinterpret_cast<const f32x4*>(partial2);
    f32x4 acc = {0.f, 0.f, 0.f, 0.f};
    #pragma unroll
    for (int s = 0; s < RED1_OUT; ++s) acc += P[(size_t)s * NF4 + j4];
    f32x4 o;
    o.x = 1.f / acc.x; o.y = 1.f / acc.y; o.z = 1.f / acc.z; o.w = 1.f / acc.w;
    const int w = j4 >> 9, u = j4 & 511;                 // un-permute slot
    reinterpret_cast<f32x4*>(c)[u * 4 + w] = o;
}

// exact fp32 epilogue from A
__global__ __launch_bounds__(THREADS, 4)
void k_finalize(const float* __restrict__ A, const float* __restrict__ r,
                const float* __restrict__ c, float* __restrict__ out) {
    const f32x4* A4 = reinterpret_cast<const f32x4*>(A);
    const f32x4* c4 = reinterpret_cast<const f32x4*>(c);
    f32x4* O4 = reinterpret_cast<f32x4*>(out);
    const size_t total = (size_t)NN * NF4;
    const size_t stride = (size_t)gridDim.x * THREADS;
    for (size_t k = (size_t)blockIdx.x * THREADS + threadIdx.x; k < total;
         k += stride) {
        const int row = (int)(k >> 11);
        const int jc = (int)(k & 2047);
        f32x4 a = __builtin_nontemporal_load(A4 + k);
        f32x4 w = c4[jc];
        const float s = r[row];
        f32x4 o = (a + EPS) * (s * w);
        __builtin_nontemporal_store(o, O4 + k);
    }
}

extern "C" void kernel_launch(void* const* d_in, const int* in_sizes, int n_in,
                              void* d_out, int out_size, void* d_ws, size_t ws_size,
                              hipStream_t stream) {
    (void)in_sizes; (void)n_in; (void)out_size;
    const float* A = (const float*)d_in[0];
    float* out = (float*)d_out;
    const dim3 g1(NF4 / THREADS, RED1_OUT);   // (8, 32)

    const size_t q_bytes = (size_t)NN * NN;   // 64 MB
    const size_t small_b = (size_t)(2 * NN + RED1_OUT * NN + NBLK * NN) * sizeof(float);

    if (ws_size >= q_bytes + small_b) {
        char* p = (char*)d_ws;
        unsigned int* Q = (unsigned int*)p;  p += q_bytes;
        float* r = (float*)p;                p += NN * sizeof(float);
        float* c = (float*)p;                p += NN * sizeof(float);
        float* partial2 = (float*)p;         p += (size_t)RED1_OUT * NN * sizeof(float);
        float* partial = (float*)p;

        k_pair_a<true, false, true><<<NBLK, THREADS, 0, stream>>>(A, Q, nullptr, r, partial);
        k_red1<<<g1, THREADS, 0, stream>>>(partial, partial2);
        k_red2<<<NF4 / THREADS, THREADS, 0, stream>>>(partial2, c);

        k_pair_q<true><<<NBLK, THREADS, 0, stream>>>(Q, c, r, partial);
        k_red1<<<g1, THREADS, 0, stream>>>(partial, partial2);
        k_red2<<<NF4 / THREADS, THREADS, 0, stream>>>(partial2, c);

        k_pair_q<false><<<NBLK, THREADS, 0, stream>>>(Q, c, r, partial);
        k_red1<<<g1, THREADS, 0, stream>>>(partial, partial2);
        k_red2<<<NF4 / THREADS, THREADS, 0, stream>>>(partial2, c);

        k_pair_q<true><<<NBLK, THREADS, 0, stream>>>(Q, c, r, partial);
        k_red1<<<g1, THREADS, 0, stream>>>(partial, partial2);
        k_red2<<<NF4 / THREADS, THREADS, 0, stream>>>(partial2, c);

        k_pair_q<false><<<NBLK, THREADS, 0, stream>>>(Q, c, r, partial);
        k_red1<<<g1, THREADS, 0, stream>>>(partial, partial2);
        k_red2<<<NF4 / THREADS, THREADS, 0, stream>>>(partial2, c);

        k_finalize<<<2048, THREADS, 0, stream>>>(A, r, c, out);
    } else {
        // fp32 fallback: all passes read A directly
        float* r = (float*)d_ws;
        float* c = r + NN;
        float* partial2 = c + NN;
        float* partial = partial2 + (size_t)RED1_OUT * NN;

        k_pair_a<true, false, false><<<NBLK, THREADS, 0, stream>>>(A, nullptr, nullptr, r, partial);
        k_red1<<<g1, THREADS, 0, stream>>>(partial, partial2);
        k_red2<<<NF4 / THREADS, THREADS, 0, stream>>>(partial2, c);

        k_pair_a<false, true, false><<<NBLK, THREADS, 0, stream>>>(A, nullptr, c, r, partial);
        k_red1<<<g1, THREADS, 0, stream>>>(partial, partial2);
        k_red2<<<NF4 / THREADS, THREADS, 0, stream>>>(partial2, c);

        k_pair_a<false, false, false><<<NBLK, THREADS, 0, stream>>>(A, nullptr, c, r, partial);
        k_red1<<<g1, THREADS, 0, stream>>>(partial, partial2);
        k_red2<<<NF4 / THREADS, THREADS, 0, stream>>>(partial2, c);

        k_pair_a<false, true, false><<<NBLK, THREADS, 0, stream>>>(A, nullptr, c, r, partial);
        k_red1<<<g1, THREADS, 0, stream>>>(partial, partial2);
        k_red2<<<NF4 / THREADS, THREADS, 0, stream>>>(partial2, c);

        k_pair_a<false, false, false><<<NBLK, THREADS, 0, stream>>>(A, nullptr, c, r, partial);
        k_red1<<<g1, THREADS, 0, stream>>>(partial, partial2);
        k_red2<<<NF4 / THREADS, THREADS, 0, stream>>>(partial2, c);

        k_finalize<<<2048, THREADS, 0, stream>>>(A, r, c, out);
    }
}